// Round 2
// baseline (1076.886 us; speedup 1.0000x reference)
//
#include <hip/hip_runtime.h>
#include <hip/hip_cooperative_groups.h>
#include <math.h>

namespace cg = cooperative_groups;

#define NB 256      // batch
#define NS 512      // seq
#define ND 256      // hidden dim
#define NL 4        // layers
#define NITERS 10
#define BD (NB*ND)
#define LDW 268     // LDS row stride in floats: (67r+k4)%8 distinct -> <=2-way b128 aliasing

// ---------------------------------------------------------------------------
// Stage a [32][256] row-major global tile into LDS [32][LDW].
// Fully coalesced: each wave-instr reads 1KB contiguous.
// ---------------------------------------------------------------------------
__device__ __forceinline__ void stage32(float* dst, const float* src, int t) {
#pragma unroll
    for (int i = 0; i < 8; ++i) {
        int idx = i * 256 + t;
        int r = idx >> 6, c = (idx & 63) << 2;
        *(float4*)&dst[r * LDW + c] = *(const float4*)&src[r * 256 + c];
    }
}

// ---------------------------------------------------------------------------
// 32x32 tile GEMM from LDS: C = sum_k A[m][k]*W[n][k]. 256 thr, 2x2/thread.
// float4 over k: 4 ds_read_b128 per 16 FMA. A-reads broadcast 16-wide.
// ---------------------------------------------------------------------------
template <class FE>
__device__ __forceinline__ void mm32(const float* As, const float* Ws, int t, FE epi) {
    const int ty = t >> 4, tx = t & 15;
    const float* a0p = As + (2 * ty) * LDW;
    const float* a1p = a0p + LDW;
    const float* w0p = Ws + (2 * tx) * LDW;
    const float* w1p = w0p + LDW;
    float acc00 = 0.f, acc01 = 0.f, acc10 = 0.f, acc11 = 0.f;
#pragma unroll 8
    for (int k = 0; k < 256; k += 4) {
        float4 a0 = *(const float4*)&a0p[k];
        float4 a1 = *(const float4*)&a1p[k];
        float4 w0 = *(const float4*)&w0p[k];
        float4 w1 = *(const float4*)&w1p[k];
        acc00 += a0.x*w0.x + a0.y*w0.y + a0.z*w0.z + a0.w*w0.w;
        acc01 += a0.x*w1.x + a0.y*w1.y + a0.z*w1.z + a0.w*w1.w;
        acc10 += a1.x*w0.x + a1.y*w0.y + a1.z*w0.z + a1.w*w0.w;
        acc11 += a1.x*w1.x + a1.y*w1.y + a1.z*w1.z + a1.w*w1.w;
    }
    epi(2 * ty, 2 * tx, acc00, acc01, acc10, acc11);
}

// ---------------------------------------------------------------------------
// K1: partial[(4b+q)][d] = sum over 128 s of emb[ids[b,s]][d] + pos[s][d]
// grid = 1024 (4 blocks per b), block = 256 -> 4 blocks/CU, 16 waves/CU.
// ---------------------------------------------------------------------------
__global__ __launch_bounds__(256) void k_pool1(const int* __restrict__ ids,
                                               const float* __restrict__ emb,
                                               const float* __restrict__ pos,
                                               float* __restrict__ partial) {
    const int bid = blockIdx.x;
    const int b = bid >> 2, q = bid & 3;
    const int t = threadIdx.x;
    __shared__ int sid[128];
    if (t < 128) sid[t] = ids[b * NS + q * 128 + t];
    __syncthreads();
    float acc = 0.f;
#pragma unroll 8
    for (int s = 0; s < 128; ++s)
        acc += emb[(size_t)sid[s] * ND + t] + pos[(q * 128 + s) * ND + t];
    partial[bid * ND + t] = acc;
}

// ---------------------------------------------------------------------------
// Cooperative kernel: pooled-reduce, init chain, 10x(predict,update),
// heads1, heads2, answerable. 256 blocks x 256 threads, 1 block/CU.
// pred_w/upd_w tiles cached in LDS across all iterations.
// ---------------------------------------------------------------------------
__global__ __launch_bounds__(256, 1) void k_coop(
    const float* partial, const float* init_w, const float* init_b,
    const float* pred_w, const float* pred_b, const float* upd_w, const float* upd_b,
    const float* sw, const float* sb, const float* ew, const float* eb,
    const float* kw, const float* kb, const float* w1, const float* b1,
    const float* w2, const float* b2,
    float* pooled, float* repsA, float* repsB, float* pred,
    float* ff, float* refined, float* sq, float* eq,
    float* sqk, float* eqk, float* sqb, float* eqb, float* h, float* out)
{
    cg::grid_group g = cg::this_grid();
    __shared__ float As[32 * LDW];
    __shared__ float Bs[32 * LDW];
    __shared__ float Pw[32 * LDW];
    __shared__ float Uw[32 * LDW];
    const int bid = blockIdx.x;
    const int t = threadIdx.x;
    const int l = bid >> 6, tile = bid & 63;
    const int m0 = (tile >> 3) * 32, n0 = (tile & 7) * 32;

    // cache this block's refinement weight tiles (rows n0..n0+31, all K)
    stage32(Pw, pred_w + (l * ND + n0) * ND, t);
    stage32(Uw, upd_w + (l * ND + n0) * ND, t);

    // ---- P0: pooled reduce ----
    {
        const float* p = partial + bid * 4 * ND + t;
        float v = p[0] + p[ND] + p[2 * ND] + p[3 * ND];
        pooled[bid * ND + t] = v * (1.f / 512.f);
    }
    g.sync();

    // ---- init chain (4 sequential layers, 64 blocks each) ----
    for (int il = 0; il < NL; ++il) {
        if (bid < 64) {
            const int im0 = (bid >> 3) * 32, in0 = (bid & 7) * 32;
            const float* srcA = (il == 0) ? pooled : repsA + (il - 1) * BD;
            __syncthreads();
            stage32(As, srcA + im0 * ND, t);
            stage32(Bs, init_w + (il * ND + in0) * ND, t);
            __syncthreads();
            float* dst = repsA + il * BD;
            mm32(As, Bs, t, [&](int my, int nx, float a00, float a01, float a10, float a11) {
                float b0 = init_b[il * ND + in0 + nx];
                float b1v = init_b[il * ND + in0 + nx + 1];
                float2 r0 = make_float2(tanhf(a00 + b0), tanhf(a01 + b1v));
                float2 r1 = make_float2(tanhf(a10 + b0), tanhf(a11 + b1v));
                float* d0 = dst + (im0 + my) * ND + in0 + nx;
                *(float2*)d0 = r0;
                *(float2*)(d0 + ND) = r1;
                if (il == NL - 1) {
                    float* d2 = ff + (im0 + my) * ND + in0 + nx;
                    *(float2*)d2 = r0;
                    *(float2*)(d2 + ND) = r1;
                }
            });
        }
        g.sync();
    }

    // ---- refinement loop ----
    float* cur = repsA;
    float* nxt = repsB;
    for (int it = 0; it < NITERS; ++it) {
        // predict: pred[l] = cur[l] @ pred_w[l]^T + pred_b[l]
        __syncthreads();
        stage32(As, cur + l * BD + m0 * ND, t);
        __syncthreads();
        mm32(As, Pw, t, [&](int my, int nx, float a00, float a01, float a10, float a11) {
            float b0 = pred_b[l * ND + n0 + nx];
            float b1v = pred_b[l * ND + n0 + nx + 1];
            float* d0 = pred + l * BD + (m0 + my) * ND + n0 + nx;
            *(float2*)d0 = make_float2(a00 + b0, a01 + b1v);
            *(float2*)(d0 + ND) = make_float2(a10 + b0, a11 + b1v);
        });
        g.sync();

        // update: nxt[l] = cur[l] + 0.1*tanh(te @ upd_w[l]^T + upd_b[l])
        __syncthreads();
        {
            const float* below = (l == 0) ? pooled : cur + (l - 1) * BD;
            const float* prd = pred + l * BD;
            const float* rp = cur + l * BD;
            const float* pra = pred + (l + 1) * BD;
            const bool hasAbove = (l < NL - 1);
#pragma unroll
            for (int i = 0; i < 8; ++i) {
                int idx = i * 256 + t;
                int r = idx >> 6, c = (idx & 63) << 2;
                int off = (m0 + r) * ND + c;
                float4 vb = *(const float4*)&below[off];
                float4 vp = *(const float4*)&prd[off];
                float4 te;
                te.x = vb.x - vp.x; te.y = vb.y - vp.y;
                te.z = vb.z - vp.z; te.w = vb.w - vp.w;
                if (hasAbove) {
                    float4 vr = *(const float4*)&rp[off];
                    float4 va = *(const float4*)&pra[off];
                    te.x += 0.5f * (vr.x - va.x); te.y += 0.5f * (vr.y - va.y);
                    te.z += 0.5f * (vr.z - va.z); te.w += 0.5f * (vr.w - va.w);
                }
                *(float4*)&As[r * LDW + c] = te;
            }
            __syncthreads();
            mm32(As, Uw, t, [&](int my, int nx, float a00, float a01, float a10, float a11) {
                float b0 = upd_b[l * ND + n0 + nx];
                float b1v = upd_b[l * ND + n0 + nx + 1];
                int o0 = (m0 + my) * ND + n0 + nx;
                float2 r0 = *(const float2*)&rp[o0];
                float2 r1 = *(const float2*)&rp[o0 + ND];
                float* d0 = nxt + l * BD + o0;
                *(float2*)d0 = make_float2(r0.x + 0.1f * tanhf(a00 + b0),
                                           r0.y + 0.1f * tanhf(a01 + b1v));
                *(float2*)(d0 + ND) = make_float2(r1.x + 0.1f * tanhf(a10 + b0),
                                                  r1.y + 0.1f * tanhf(a11 + b1v));
            });
        }
        g.sync();
        float* tmp = cur; cur = nxt; nxt = tmp;
    }
    // after even # of swaps, final reps = cur

    // ---- heads1: refined = cur[3]+ff; sq/eq = refined @ {sw,ew}^T + bias ----
    if (bid < 128) {
        const int half = bid >> 6;
        const int htile = bid & 63;
        const int hm0 = (htile >> 3) * 32, hn0 = (htile & 7) * 32;
        const float* r3 = cur + 3 * BD;
        const bool wr = (half == 0) && ((htile & 7) == 0);
        __syncthreads();
#pragma unroll
        for (int i = 0; i < 8; ++i) {
            int idx = i * 256 + t;
            int r = idx >> 6, c = (idx & 63) << 2;
            int off = (hm0 + r) * ND + c;
            float4 v = *(const float4*)&r3[off];
            float4 f = *(const float4*)&ff[off];
            v.x += f.x; v.y += f.y; v.z += f.z; v.w += f.w;
            *(float4*)&As[r * LDW + c] = v;
            if (wr) *(float4*)&refined[off] = v;
        }
        stage32(Bs, (half ? ew : sw) + hn0 * ND, t);
        __syncthreads();
        const float* bias = half ? eb : sb;
        float* dst = half ? eq : sq;
        mm32(As, Bs, t, [&](int my, int nx, float a00, float a01, float a10, float a11) {
            float b0 = bias[hn0 + nx], b1v = bias[hn0 + nx + 1];
            float* d0 = dst + (hm0 + my) * ND + hn0 + nx;
            *(float2*)d0 = make_float2(a00 + b0, a01 + b1v);
            *(float2*)(d0 + ND) = make_float2(a10 + b0, a11 + b1v);
        });
    }
    g.sync();

    // ---- heads2: sqk/eqk = {sq,eq} @ kw (non-T); h = gelu(refined@w1^T+b1);
    //      sqb/eqb = {sq,eq}·kb ----
    if (bid < 128) {
        const int half = bid >> 6;
        const int htile = bid & 63;
        const int hm0 = (htile >> 3) * 32, hn0 = (htile & 7) * 32;
        __syncthreads();
        stage32(As, (half ? eq : sq) + hm0 * ND, t);
        {   // transpose-stage: Bs[r][k] = kw[k][hn0+r]
            int r = t & 31, kk = t >> 5;
#pragma unroll 4
            for (int i = 0; i < 32; ++i) {
                int k = i * 8 + kk;
                Bs[r * LDW + k] = kw[k * ND + hn0 + r];
            }
        }
        __syncthreads();
        float* dst = half ? eqk : sqk;
        mm32(As, Bs, t, [&](int my, int nx, float a00, float a01, float a10, float a11) {
            float* d0 = dst + (hm0 + my) * ND + hn0 + nx;
            *(float2*)d0 = make_float2(a00, a01);
            *(float2*)(d0 + ND) = make_float2(a10, a11);
        });
    } else if (bid < 160) {
        const int htile = bid - 128;
        const int hm0 = (htile >> 2) * 32, hn0 = (htile & 3) * 32;
        __syncthreads();
        stage32(As, refined + hm0 * ND, t);
        stage32(Bs, w1 + hn0 * ND, t);
        __syncthreads();
        mm32(As, Bs, t, [&](int my, int nx, float a00, float a01, float a10, float a11) {
            float b0 = b1[hn0 + nx], b1v = b1[hn0 + nx + 1];
            float x00 = a00 + b0, x01 = a01 + b1v, x10 = a10 + b0, x11 = a11 + b1v;
            float* d0 = h + (hm0 + my) * 128 + hn0 + nx;
            const float c = 0.70710678118654752f;
            *(float2*)d0 = make_float2(0.5f * x00 * (1.f + erff(x00 * c)),
                                       0.5f * x01 * (1.f + erff(x01 * c)));
            *(float2*)(d0 + 128) = make_float2(0.5f * x10 * (1.f + erff(x10 * c)),
                                               0.5f * x11 * (1.f + erff(x11 * c)));
        });
    } else if (bid == 160) {
        const int b = t;
        float a = 0.f, e = 0.f;
#pragma unroll 4
        for (int k = 0; k < ND; k += 4) {
            float4 vs = *(const float4*)&sq[b * ND + k];
            float4 ve = *(const float4*)&eq[b * ND + k];
            float4 vk = *(const float4*)&kb[k];
            a += vs.x*vk.x + vs.y*vk.y + vs.z*vk.z + vs.w*vk.w;
            e += ve.x*vk.x + ve.y*vk.y + ve.z*vk.z + ve.w*vk.w;
        }
        sqb[b] = a; eqb[b] = e;
    }
    g.sync();

    // ---- answerable logits ----
    if (bid == 0) {
        const int b = t;
        float a0 = b2[0], a1 = b2[1];
#pragma unroll 4
        for (int j = 0; j < 128; j += 4) {
            float4 hv = *(const float4*)&h[b * 128 + j];
            float4 wa = *(const float4*)&w2[j];
            float4 wb = *(const float4*)&w2[128 + j];
            a0 += hv.x*wa.x + hv.y*wa.y + hv.z*wa.z + hv.w*wa.w;
            a1 += hv.x*wb.x + hv.y*wb.y + hv.z*wb.z + hv.w*wb.w;
        }
        out[2 * NB * NS + 2 * b] = a0;
        out[2 * NB * NS + 2 * b + 1] = a1;
    }
}

// ---------------------------------------------------------------------------
// logits gather: out0/out1[b,s] = (emb[ids[b,s]]+pos[s])·{sqk,eqk}[b] + {sqb,eqb}[b]
// grid = 1024 (4 blocks per b), block = 512 -> 2 blocks/CU, 16 waves/CU
// ---------------------------------------------------------------------------
__global__ __launch_bounds__(512) void k_logits(const int* __restrict__ ids,
                                                const float* __restrict__ emb,
                                                const float* __restrict__ pos,
                                                const float* __restrict__ sqk,
                                                const float* __restrict__ eqk,
                                                const float* __restrict__ sqb,
                                                const float* __restrict__ eqb,
                                                float* __restrict__ out) {
    const int bid = blockIdx.x;
    const int b = bid >> 2, q = bid & 3;
    const int t = threadIdx.x;
    __shared__ float sk[ND], ek[ND];
    __shared__ int sid[128];
    if (t < 256) sk[t] = sqk[b * ND + t];
    else ek[t - 256] = eqk[b * ND + t - 256];
    if (t < 128) sid[t] = ids[b * NS + q * 128 + t];
    __syncthreads();
    const int w = t >> 6, lane = t & 63;
    const float4 ks = *(const float4*)&sk[4 * lane];
    const float4 ke = *(const float4*)&ek[4 * lane];
    const float qbs = sqb[b], qbe = eqb[b];
    for (int si = w; si < 128; si += 8) {
        const int s = q * 128 + si;
        const int id = sid[si];
        const float4 e4 = *(const float4*)&emb[(size_t)id * ND + 4 * lane];
        const float4 p4 = *(const float4*)&pos[s * ND + 4 * lane];
        float vx = e4.x + p4.x, vy = e4.y + p4.y, vz = e4.z + p4.z, vw = e4.w + p4.w;
        float ds = vx*ks.x + vy*ks.y + vz*ks.z + vw*ks.w;
        float de = vx*ke.x + vy*ke.y + vz*ke.z + vw*ke.w;
#pragma unroll
        for (int off = 32; off >= 1; off >>= 1) {
            ds += __shfl_xor(ds, off);
            de += __shfl_xor(de, off);
        }
        if (lane == 0) {
            out[b * NS + s] = ds + qbs;
            out[NB * NS + b * NS + s] = de + qbe;
        }
    }
}

// ---------------------------------------------------------------------------
extern "C" void kernel_launch(void* const* d_in, const int* in_sizes, int n_in,
                              void* d_out, int out_size, void* d_ws, size_t ws_size,
                              hipStream_t stream) {
    const int*   ids    = (const int*)d_in[0];
    const float* emb    = (const float*)d_in[1];
    const float* pos    = (const float*)d_in[2];
    const float* init_w = (const float*)d_in[3];
    const float* init_b = (const float*)d_in[4];
    const float* pred_w = (const float*)d_in[5];
    const float* pred_b = (const float*)d_in[6];
    const float* upd_w  = (const float*)d_in[7];
    const float* upd_b  = (const float*)d_in[8];
    const float* sw     = (const float*)d_in[9];
    const float* sb     = (const float*)d_in[10];
    const float* ew     = (const float*)d_in[11];
    const float* eb     = (const float*)d_in[12];
    const float* kw     = (const float*)d_in[13];
    const float* kb     = (const float*)d_in[14];
    const float* w1     = (const float*)d_in[15];
    const float* b1     = (const float*)d_in[16];
    const float* w2     = (const float*)d_in[17];
    const float* b2     = (const float*)d_in[18];
    float* out = (float*)d_out;

    float* ws = (float*)d_ws;
    float* pooled  = ws;
    float* repsA   = pooled + BD;
    float* repsB   = repsA + NL * BD;
    float* pred    = repsB + NL * BD;     // 4*BD floats
    float* ff      = pred + NL * BD;
    float* refined = ff + BD;
    float* sq      = refined + BD;
    float* eq      = sq + BD;
    float* sqk     = eq + BD;
    float* eqk     = sqk + BD;
    float* sqb     = eqk + BD;
    float* eqb     = sqb + NB;
    float* h       = eqb + NB;
    float* partial = pred;                // alias: partial consumed before pred written

    k_pool1<<<1024, 256, 0, stream>>>(ids, emb, pos, partial);

    void* args[] = {
        (void*)&partial, (void*)&init_w, (void*)&init_b,
        (void*)&pred_w, (void*)&pred_b, (void*)&upd_w, (void*)&upd_b,
        (void*)&sw, (void*)&sb, (void*)&ew, (void*)&eb,
        (void*)&kw, (void*)&kb, (void*)&w1, (void*)&b1,
        (void*)&w2, (void*)&b2,
        (void*)&pooled, (void*)&repsA, (void*)&repsB, (void*)&pred,
        (void*)&ff, (void*)&refined, (void*)&sq, (void*)&eq,
        (void*)&sqk, (void*)&eqk, (void*)&sqb, (void*)&eqb, (void*)&h, (void*)&out
    };
    hipLaunchCooperativeKernel((void*)k_coop, dim3(256), dim3(256), args, 0, stream);

    k_logits<<<1024, 512, 0, stream>>>(ids, emb, pos, sqk, eqk, sqb, eqb, out);
}

// Round 3
// 678.561 us; speedup vs baseline: 1.5870x; 1.5870x over previous
//
#include <hip/hip_runtime.h>
#include <math.h>

#define NB 256      // batch
#define NS 512      // seq
#define ND 256      // hidden dim
#define NL 4        // layers
#define NITERS 10

// ---------------------------------------------------------------------------
// apply_half: o{0,1} = sum over 128 k of W[k]*x{0,1}[k]
// Thread owns one output column; W streamed from global (L2-resident row),
// x read from LDS with same-address-all-lanes reads (HW broadcast, no
// conflicts). 2 sub-accumulators per row for FMA-latency ILP.
// ---------------------------------------------------------------------------
__device__ __forceinline__ void apply_half(const float* __restrict__ Wrow,
                                           const float* x0, const float* x1,
                                           float& o0, float& o1) {
    float a0 = 0.f, b0 = 0.f, a1 = 0.f, b1 = 0.f;
#pragma unroll 4
    for (int k = 0; k < 128; k += 8) {
        float4 w0 = *(const float4*)(Wrow + k);
        float4 w1 = *(const float4*)(Wrow + k + 4);
        float4 p0 = *(const float4*)(x0 + k);
        float4 p1 = *(const float4*)(x0 + k + 4);
        float4 q0 = *(const float4*)(x1 + k);
        float4 q1 = *(const float4*)(x1 + k + 4);
        a0 += w0.x*p0.x + w0.y*p0.y + w0.z*p0.z + w0.w*p0.w;
        b0 += w1.x*p1.x + w1.y*p1.y + w1.z*p1.z + w1.w*p1.w;
        a1 += w0.x*q0.x + w0.y*q0.y + w0.z*q0.z + w0.w*q0.w;
        b1 += w1.x*q1.x + w1.y*q1.y + w1.z*q1.z + w1.w*q1.w;
    }
    o0 = a0 + b0; o1 = a1 + b1;
}

// ---------------------------------------------------------------------------
// K1: partial[(4b+q)][d] = sum over 128 s of emb[ids[b,s]][d] + pos[s][d]
// ---------------------------------------------------------------------------
__global__ __launch_bounds__(256) void k_pool1(const int* __restrict__ ids,
                                               const float* __restrict__ emb,
                                               const float* __restrict__ pos,
                                               float* __restrict__ partial) {
    const int bid = blockIdx.x;
    const int b = bid >> 2, q = bid & 3;
    const int t = threadIdx.x;
    __shared__ int sid[128];
    if (t < 128) sid[t] = ids[b * NS + q * 128 + t];
    __syncthreads();
    float acc = 0.f;
#pragma unroll 8
    for (int s = 0; s < 128; ++s)
        acc += emb[(size_t)sid[s] * ND + t] + pos[(q * 128 + s) * ND + t];
    partial[bid * ND + t] = acc;
}

// ---------------------------------------------------------------------------
// k_chain: per-row-independent middle section. 128 blocks x 512 threads.
// Block bid owns rows 2*bid, 2*bid+1. thread: d = t&255 (output col),
// h = t>>8 (k-half for applies; row selector for elementwise steps).
// All row state lives in LDS; weights streamed from L2 each use.
// ---------------------------------------------------------------------------
__global__ __launch_bounds__(512) void k_chain(
    const float* __restrict__ partial,
    const float* __restrict__ init_w, const float* __restrict__ init_b,
    const float* __restrict__ pred_w, const float* __restrict__ pred_b,
    const float* __restrict__ upd_w,  const float* __restrict__ upd_b,
    const float* __restrict__ sw, const float* __restrict__ sb,
    const float* __restrict__ ew, const float* __restrict__ eb,
    const float* __restrict__ kw, const float* __restrict__ kb,
    const float* __restrict__ w1, const float* __restrict__ b1,
    const float* __restrict__ w2, const float* __restrict__ b2,
    float* __restrict__ sqk, float* __restrict__ eqk,
    float* __restrict__ sqb, float* __restrict__ eqb,
    float* __restrict__ out)
{
    __shared__ float pooled[2][ND];
    __shared__ float curbuf[2][2][NL][ND];   // [parity][row][layer][d]
    __shared__ float prd[2][NL][ND];         // [row][layer][d]
    __shared__ float ffs[2][ND];
    __shared__ float xscr[2][NL][ND];        // te vectors
    __shared__ float comb[NL][2][ND];        // split-k partials from h=1
    __shared__ float refined[2][ND];
    __shared__ float seq[2][ND][2];          // [row][k][{sq,eq}] interleaved
    __shared__ float red[4][ND];
    __shared__ float hcomb[4][2][128];
    __shared__ float hls[2][128];

    const int t = threadIdx.x;
    const int d = t & 255;
    const int h = t >> 8;
    const int bid = blockIdx.x;
    const int r0 = bid * 2;

    // preload per-d biases for the loop
    float pbr[NL], ubr[NL];
#pragma unroll
    for (int l = 0; l < NL; ++l) { pbr[l] = pred_b[l*ND+d]; ubr[l] = upd_b[l*ND+d]; }

    // ---- pooled reduce (row = h) ----
    {
        const float* p = partial + (size_t)(r0 + h) * 4 * ND + d;
        pooled[h][d] = (p[0] + p[ND] + p[2*ND] + p[3*ND]) * (1.f/512.f);
    }
    __syncthreads();

    // ---- init chain ----
    for (int il = 0; il < NL; ++il) {
        const float* x0 = (il == 0) ? &pooled[0][h*128] : &curbuf[0][0][il-1][h*128];
        const float* x1 = (il == 0) ? &pooled[1][h*128] : &curbuf[0][1][il-1][h*128];
        float a0, a1;
        apply_half(init_w + ((size_t)(il*ND + d))*ND + h*128, x0, x1, a0, a1);
        if (h) { comb[0][0][d] = a0; comb[0][1][d] = a1; }
        __syncthreads();
        if (!h) {
            float ib = init_b[il*ND + d];
            float v0 = tanhf(a0 + comb[0][0][d] + ib);
            float v1 = tanhf(a1 + comb[0][1][d] + ib);
            curbuf[0][0][il][d] = v0; curbuf[0][1][il][d] = v1;
            if (il == NL-1) { ffs[0][d] = v0; ffs[1][d] = v1; }
        }
        __syncthreads();
    }

    // ---- refinement loop (no cross-block deps!) ----
    int par = 0;
    for (int it = 0; it < NITERS; ++it) {
        // predict, all 4 layers back-to-back
        float pa[NL][2];
#pragma unroll
        for (int l = 0; l < NL; ++l)
            apply_half(pred_w + ((size_t)(l*ND + d))*ND + h*128,
                       &curbuf[par][0][l][h*128], &curbuf[par][1][l][h*128],
                       pa[l][0], pa[l][1]);
        if (h) {
#pragma unroll
            for (int l = 0; l < NL; ++l) { comb[l][0][d] = pa[l][0]; comb[l][1][d] = pa[l][1]; }
        }
        __syncthreads();
        if (!h) {
#pragma unroll
            for (int l = 0; l < NL; ++l) {
                prd[0][l][d] = pa[l][0] + comb[l][0][d] + pbr[l];
                prd[1][l][d] = pa[l][1] + comb[l][1][d] + pbr[l];
            }
        }
        __syncthreads();

        // total errors (row = h)
#pragma unroll
        for (int l = 0; l < NL; ++l) {
            float below = (l == 0) ? pooled[h][d] : curbuf[par][h][l-1][d];
            float te = below - prd[h][l][d];
            if (l < NL-1) te += 0.5f * (curbuf[par][h][l][d] - prd[h][l+1][d]);
            xscr[h][l][d] = te;
        }
        __syncthreads();

        // update, all 4 layers
        float ua[NL][2];
#pragma unroll
        for (int l = 0; l < NL; ++l)
            apply_half(upd_w + ((size_t)(l*ND + d))*ND + h*128,
                       &xscr[0][l][h*128], &xscr[1][l][h*128],
                       ua[l][0], ua[l][1]);
        if (h) {
#pragma unroll
            for (int l = 0; l < NL; ++l) { comb[l][0][d] = ua[l][0]; comb[l][1][d] = ua[l][1]; }
        }
        __syncthreads();
        if (!h) {
#pragma unroll
            for (int l = 0; l < NL; ++l) {
                curbuf[par^1][0][l][d] = curbuf[par][0][l][d] + 0.1f*tanhf(ua[l][0] + comb[l][0][d] + ubr[l]);
                curbuf[par^1][1][l][d] = curbuf[par][1][l][d] + 0.1f*tanhf(ua[l][1] + comb[l][1][d] + ubr[l]);
            }
        }
        __syncthreads();
        par ^= 1;
    }

    // ---- heads ----
    refined[h][d] = curbuf[par][h][3][d] + ffs[h][d];
    __syncthreads();

    // sq / eq
    {
        float sa0, sa1, ea0, ea1;
        apply_half(sw + (size_t)d*ND + h*128, &refined[0][h*128], &refined[1][h*128], sa0, sa1);
        apply_half(ew + (size_t)d*ND + h*128, &refined[0][h*128], &refined[1][h*128], ea0, ea1);
        if (h) { comb[0][0][d]=sa0; comb[0][1][d]=sa1; comb[1][0][d]=ea0; comb[1][1][d]=ea1; }
        __syncthreads();
        if (!h) {
            float s0 = sa0 + comb[0][0][d] + sb[d], s1 = sa1 + comb[0][1][d] + sb[d];
            float e0 = ea0 + comb[1][0][d] + eb[d], e1 = ea1 + comb[1][1][d] + eb[d];
            seq[0][d][0] = s0; seq[0][d][1] = e0;
            seq[1][d][0] = s1; seq[1][d][1] = e1;
        }
        __syncthreads();
    }

    // sqk/eqk = {sq,eq} @ kw (sum over kw row index); kw col reads are
    // coalesced across threads (consecutive d at fixed k).
    {
        float as0=0.f, ae0=0.f, as1=0.f, ae1=0.f;
        const int kbase = h * 128;
#pragma unroll 4
        for (int k = 0; k < 128; ++k) {
            float kv = kw[(size_t)(kbase + k)*ND + d];
            float2 se0 = *(const float2*)&seq[0][kbase + k][0];
            float2 se1 = *(const float2*)&seq[1][kbase + k][0];
            as0 += kv * se0.x; ae0 += kv * se0.y;
            as1 += kv * se1.x; ae1 += kv * se1.y;
        }
        if (h) { comb[0][0][d]=as0; comb[0][1][d]=as1; comb[1][0][d]=ae0; comb[1][1][d]=ae1; }
        __syncthreads();
        if (!h) {
            sqk[(size_t)r0*ND + d]     = as0 + comb[0][0][d];
            sqk[(size_t)(r0+1)*ND + d] = as1 + comb[0][1][d];
            eqk[(size_t)r0*ND + d]     = ae0 + comb[1][0][d];
            eqk[(size_t)(r0+1)*ND + d] = ae1 + comb[1][1][d];
        }
    }

    // sqb/eqb = {sq,eq}·kb  (row = h)
    {
        float kbv = kb[d];
        red[h*2 + 0][d] = seq[h][d][0] * kbv;
        red[h*2 + 1][d] = seq[h][d][1] * kbv;
        __syncthreads();
        const int w = t >> 6, lane = t & 63;
        if (w < 4) {
            float v = red[w][lane] + red[w][lane+64] + red[w][lane+128] + red[w][lane+192];
#pragma unroll
            for (int off = 32; off >= 1; off >>= 1) v += __shfl_xor(v, off);
            if (lane == 0) {
                float* dstp = (w & 1) ? eqb : sqb;
                dstp[r0 + (w >> 1)] = v;
            }
        }
        __syncthreads();
    }

    // h = gelu_exact(refined @ w1^T + b1)  [2 rows x 128]
    {
        const int j = t & 127, seg = t >> 7;   // seg in 0..3 = k-quarter
        float a0 = 0.f, a1 = 0.f;
        const float* wr = w1 + (size_t)j*ND + seg*64;
        const float* x0p = &refined[0][seg*64];
        const float* x1p = &refined[1][seg*64];
#pragma unroll 4
        for (int k = 0; k < 64; k += 4) {
            float4 wv = *(const float4*)(wr + k);
            float4 p4 = *(const float4*)(x0p + k);
            float4 q4 = *(const float4*)(x1p + k);
            a0 += wv.x*p4.x + wv.y*p4.y + wv.z*p4.z + wv.w*p4.w;
            a1 += wv.x*q4.x + wv.y*q4.y + wv.z*q4.z + wv.w*q4.w;
        }
        hcomb[seg][0][j] = a0; hcomb[seg][1][j] = a1;
        __syncthreads();
        if (t < 256) {
            const int rr = t >> 7, jj = t & 127;
            float x = hcomb[0][rr][jj] + hcomb[1][rr][jj] + hcomb[2][rr][jj]
                    + hcomb[3][rr][jj] + b1[jj];
            hls[rr][jj] = 0.5f * x * (1.f + erff(x * 0.70710678118654752f));
        }
        __syncthreads();
    }

    // answerable logits
    {
        const int w = t >> 6, lane = t & 63;
        if (w < 4) {
            const int rr = w >> 1, j2 = w & 1;
            float v = hls[rr][lane]      * w2[j2*128 + lane]
                    + hls[rr][lane + 64] * w2[j2*128 + lane + 64];
#pragma unroll
            for (int off = 32; off >= 1; off >>= 1) v += __shfl_xor(v, off);
            if (lane == 0) out[2*NB*NS + (r0 + rr)*2 + j2] = v + b2[j2];
        }
    }
}

// ---------------------------------------------------------------------------
// logits gather: out0/out1[b,s] = (emb[ids[b,s]]+pos[s])·{sqk,eqk}[b] + {sqb,eqb}[b]
// grid = 1024 (4 blocks per b), block = 512
// ---------------------------------------------------------------------------
__global__ __launch_bounds__(512) void k_logits(const int* __restrict__ ids,
                                                const float* __restrict__ emb,
                                                const float* __restrict__ pos,
                                                const float* __restrict__ sqk,
                                                const float* __restrict__ eqk,
                                                const float* __restrict__ sqb,
                                                const float* __restrict__ eqb,
                                                float* __restrict__ out) {
    const int bid = blockIdx.x;
    const int b = bid >> 2, q = bid & 3;
    const int t = threadIdx.x;
    __shared__ float sk[ND], ek[ND];
    __shared__ int sid[128];
    if (t < 256) sk[t] = sqk[b * ND + t];
    else ek[t - 256] = eqk[b * ND + t - 256];
    if (t < 128) sid[t] = ids[b * NS + q * 128 + t];
    __syncthreads();
    const int w = t >> 6, lane = t & 63;
    const float4 ks = *(const float4*)&sk[4 * lane];
    const float4 ke = *(const float4*)&ek[4 * lane];
    const float qbs = sqb[b], qbe = eqb[b];
    for (int si = w; si < 128; si += 8) {
        const int s = q * 128 + si;
        const int id = sid[si];
        const float4 e4 = *(const float4*)&emb[(size_t)id * ND + 4 * lane];
        const float4 p4 = *(const float4*)&pos[s * ND + 4 * lane];
        float vx = e4.x + p4.x, vy = e4.y + p4.y, vz = e4.z + p4.z, vw = e4.w + p4.w;
        float ds = vx*ks.x + vy*ks.y + vz*ks.z + vw*ks.w;
        float de = vx*ke.x + vy*ke.y + vz*ke.z + vw*ke.w;
#pragma unroll
        for (int off = 32; off >= 1; off >>= 1) {
            ds += __shfl_xor(ds, off);
            de += __shfl_xor(de, off);
        }
        if (lane == 0) {
            out[b * NS + s] = ds + qbs;
            out[NB * NS + b * NS + s] = de + qbe;
        }
    }
}

// ---------------------------------------------------------------------------
extern "C" void kernel_launch(void* const* d_in, const int* in_sizes, int n_in,
                              void* d_out, int out_size, void* d_ws, size_t ws_size,
                              hipStream_t stream) {
    const int*   ids    = (const int*)d_in[0];
    const float* emb    = (const float*)d_in[1];
    const float* pos    = (const float*)d_in[2];
    const float* init_w = (const float*)d_in[3];
    const float* init_b = (const float*)d_in[4];
    const float* pred_w = (const float*)d_in[5];
    const float* pred_b = (const float*)d_in[6];
    const float* upd_w  = (const float*)d_in[7];
    const float* upd_b  = (const float*)d_in[8];
    const float* sw     = (const float*)d_in[9];
    const float* sb     = (const float*)d_in[10];
    const float* ew     = (const float*)d_in[11];
    const float* eb     = (const float*)d_in[12];
    const float* kw     = (const float*)d_in[13];
    const float* kb     = (const float*)d_in[14];
    const float* w1     = (const float*)d_in[15];
    const float* b1     = (const float*)d_in[16];
    const float* w2     = (const float*)d_in[17];
    const float* b2     = (const float*)d_in[18];
    float* out = (float*)d_out;

    float* ws = (float*)d_ws;
    float* partial = ws;                    // 1024*256
    float* sqk     = partial + 1024 * ND;   // 256*256
    float* eqk     = sqk + NB * ND;         // 256*256
    float* sqb     = eqk + NB * ND;         // 256
    float* eqb     = sqb + NB;              // 256

    k_pool1<<<1024, 256, 0, stream>>>(ids, emb, pos, partial);

    k_chain<<<128, 512, 0, stream>>>(partial, init_w, init_b,
                                     pred_w, pred_b, upd_w, upd_b,
                                     sw, sb, ew, eb, kw, kb, w1, b1, w2, b2,
                                     sqk, eqk, sqb, eqb, out);

    k_logits<<<1024, 512, 0, stream>>>(ids, emb, pos, sqk, eqk, sqb, eqb, out);
}

// Round 4
// 574.239 us; speedup vs baseline: 1.8753x; 1.1817x over previous
//
#include <hip/hip_runtime.h>
#include <math.h>

#define NB 256
#define NS 512
#define ND 256
#define NL 4
#define NITERS 10
#define DD (ND*ND)      // 65536
#define LDA 772         // LDS row stride for stage kernel (16 rows x up to 768 k)

// ---------------------------------------------------------------------------
// K1: partial[(4b+q)][d] = sum over 128 s of emb[ids[b,s]][d] + pos[s][d]
// ---------------------------------------------------------------------------
__global__ __launch_bounds__(256) void k_pool1(const int* __restrict__ ids,
                                               const float* __restrict__ emb,
                                               const float* __restrict__ pos,
                                               float* __restrict__ partial) {
    const int bid = blockIdx.x;
    const int b = bid >> 2, q = bid & 3;
    const int t = threadIdx.x;
    __shared__ int sid[128];
    if (t < 128) sid[t] = ids[b * NS + q * 128 + t];
    __syncthreads();
    float acc = 0.f;
#pragma unroll 8
    for (int s = 0; s < 128; ++s)
        acc += emb[(size_t)sid[s] * ND + t] + pos[(q * 128 + s) * ND + t];
    partial[bid * ND + t] = acc;
}

// ---------------------------------------------------------------------------
// k_prep: precompute combined matrices (stored TRANSPOSED [k][d] for
// coalesced apply), transposed init weights, head fold-ins, const vectors.
//   CM slots (each DD floats): 0:G0 1:H0 3:U1t 4:G1 5:H1 6:U2t 7:G2 8:H2
//                              9:U3t 10:G3      (G=0.5U-UP, H=-0.5UP')
//   rc0[row][d] = (U0 . pooled_row)[d]
//   KSt[f][e] = sum_k sw[k][f]*kw[k][e]  (sqk = KSt^T-apply(refined)+ksb)
// ---------------------------------------------------------------------------
__global__ __launch_bounds__(256) void k_prep(
    const float* __restrict__ pred_w, const float* __restrict__ pred_b,
    const float* __restrict__ upd_w,  const float* __restrict__ upd_b,
    const float* __restrict__ init_w,
    const float* __restrict__ sw, const float* __restrict__ sb,
    const float* __restrict__ ew, const float* __restrict__ eb,
    const float* __restrict__ kw, const float* __restrict__ kb,
    const float* __restrict__ w1,
    const float* __restrict__ partial,
    float* __restrict__ CM, float* __restrict__ CMI,
    float* __restrict__ KSt, float* __restrict__ KEt, float* __restrict__ W1t,
    float* __restrict__ cvec, float* __restrict__ rc0,
    float* __restrict__ vsk, float* __restrict__ vse,
    float* __restrict__ ksb, float* __restrict__ keb, float* __restrict__ scal)
{
    const int bid = blockIdx.x;
    const int t = threadIdx.x;

    if (bid < 576 || (bid >= 1056 && bid < 1120)) {
        // -------- GEMM blocks: OUT[i][j] = alpha*sum_e A(e,i)*B(j|e) + tau*T[j][i]
        int id, tile;
        if (bid < 576) { id = bid >> 6; tile = bid & 63; }
        else           { id = 9;        tile = bid - 1056; }
        const float* Asrc = nullptr; const float* Bsrc = nullptr;
        float alpha = 1.f, tau = 0.f; float* outp = nullptr;
        bool bT = false, aPool = false;
        switch (id) {
            case 0: Asrc = pred_w;        Bsrc = upd_w;        alpha=-1.f;  tau=0.5f; outp = CM + 0*(size_t)DD; break;
            case 1: Asrc = pred_w + DD;   Bsrc = upd_w;        alpha=-0.5f;           outp = CM + 1*(size_t)DD; break;
            case 2: Asrc = pred_w + DD;   Bsrc = upd_w + DD;   alpha=-1.f;  tau=0.5f; outp = CM + 4*(size_t)DD; break;
            case 3: Asrc = pred_w + 2*DD; Bsrc = upd_w + DD;   alpha=-0.5f;           outp = CM + 5*(size_t)DD; break;
            case 4: Asrc = pred_w + 2*DD; Bsrc = upd_w + 2*DD; alpha=-1.f;  tau=0.5f; outp = CM + 7*(size_t)DD; break;
            case 5: Asrc = pred_w + 3*DD; Bsrc = upd_w + 2*DD; alpha=-0.5f;           outp = CM + 8*(size_t)DD; break;
            case 6: Asrc = pred_w + 3*DD; Bsrc = upd_w + 3*DD; alpha=-1.f;            outp = CM + 10*(size_t)DD; break;
            case 7: Asrc = sw; Bsrc = kw; bT = true; outp = KSt; break;
            case 8: Asrc = ew; Bsrc = kw; bT = true; outp = KEt; break;
            default: Bsrc = upd_w; aPool = true; outp = rc0; break; // rc0: A=pooled(from partial), B=U0
        }
        const float* Tsrc = (tau != 0.f) ? Bsrc : nullptr;
        const int i0 = (tile >> 3) * 32, j0 = (tile & 7) * 32;
        __shared__ float As[32 * 33];
        __shared__ float Bs[32 * 33];
        const int tx = t & 15, ty = t >> 4;
        float a00 = 0.f, a01 = 0.f, a10 = 0.f, a11 = 0.f;
        for (int e0 = 0; e0 < 256; e0 += 32) {
            __syncthreads();
            if (!aPool) { // T-form: As[e][i] = Asrc[e][i] (lanes i coalesced)
                const int ii = t & 31, e8 = t >> 5;
#pragma unroll
                for (int p = 0; p < 4; ++p) {
                    int ee = e8 + 8 * p;
                    As[ee * 33 + ii] = Asrc[(size_t)(e0 + ee) * 256 + i0 + ii];
                }
            } else {      // pooled rows from partial (lanes e coalesced)
                const int ee = t & 31, i8 = t >> 5;
#pragma unroll
                for (int p = 0; p < 4; ++p) {
                    int ii = i8 + 8 * p;
                    const float* pp = partial + (size_t)(i0 + ii) * 4 * 256 + e0 + ee;
                    As[ee * 33 + ii] = (pp[0] + pp[256] + pp[512] + pp[768]) * (1.f / 512.f);
                }
            }
            if (!bT) {    // N-form: Bs[e][j] = Bsrc[j][e] (lanes e coalesced)
                const int ee = t & 31, j8 = t >> 5;
#pragma unroll
                for (int p = 0; p < 4; ++p) {
                    int jj = j8 + 8 * p;
                    Bs[ee * 33 + jj] = Bsrc[(size_t)(j0 + jj) * 256 + e0 + ee];
                }
            } else {      // T-form: Bs[e][j] = Bsrc[e][j] (lanes j coalesced)
                const int jj = t & 31, e8 = t >> 5;
#pragma unroll
                for (int p = 0; p < 4; ++p) {
                    int ee = e8 + 8 * p;
                    Bs[ee * 33 + jj] = Bsrc[(size_t)(e0 + ee) * 256 + j0 + jj];
                }
            }
            __syncthreads();
#pragma unroll
            for (int e = 0; e < 32; ++e) {
                float va0 = As[e * 33 + 2 * ty], va1 = As[e * 33 + 2 * ty + 1];
                float vb0 = Bs[e * 33 + 2 * tx], vb1 = Bs[e * 33 + 2 * tx + 1];
                a00 += va0 * vb0; a01 += va0 * vb1;
                a10 += va1 * vb0; a11 += va1 * vb1;
            }
        }
        float t00 = 0.f, t01 = 0.f, t10 = 0.f, t11 = 0.f;
        if (Tsrc) {
            t00 = Tsrc[(size_t)(j0 + 2 * tx) * 256 + i0 + 2 * ty];
            t01 = Tsrc[(size_t)(j0 + 2 * tx + 1) * 256 + i0 + 2 * ty];
            t10 = Tsrc[(size_t)(j0 + 2 * tx) * 256 + i0 + 2 * ty + 1];
            t11 = Tsrc[(size_t)(j0 + 2 * tx + 1) * 256 + i0 + 2 * ty + 1];
        }
        outp[(size_t)(i0 + 2 * ty) * 256 + j0 + 2 * tx]         = alpha * a00 + tau * t00;
        outp[(size_t)(i0 + 2 * ty) * 256 + j0 + 2 * tx + 1]     = alpha * a01 + tau * t01;
        outp[(size_t)(i0 + 2 * ty + 1) * 256 + j0 + 2 * tx]     = alpha * a10 + tau * t10;
        outp[(size_t)(i0 + 2 * ty + 1) * 256 + j0 + 2 * tx + 1] = alpha * a11 + tau * t11;
        return;
    }

    if (bid < 1024) {
        // -------- 256x256 transposes: 7 matrices (U1,U2,U3 -> CM 3/6/9; IW0-3 -> CMI)
        const int tid = bid - 576;
        const int m = tid >> 6, tile = tid & 63;
        const float* src; float* dst;
        if (m < 3) { src = upd_w + (size_t)(m + 1) * DD; dst = CM + (size_t)(3 + 3 * m) * DD; }
        else       { src = init_w + (size_t)(m - 3) * DD; dst = CMI + (size_t)(m - 3) * DD; }
        const int r0 = (tile >> 3) * 32, c0 = (tile & 7) * 32;
        __shared__ float T[32 * 33];
        const int cc = t & 31, r8 = t >> 5;
#pragma unroll
        for (int p = 0; p < 4; ++p) {
            int rr = r8 + 8 * p;
            T[rr * 33 + cc] = src[(size_t)(r0 + rr) * 256 + c0 + cc];
        }
        __syncthreads();
#pragma unroll
        for (int p = 0; p < 4; ++p) {
            int rr = r8 + 8 * p;
            dst[(size_t)(c0 + rr) * 256 + r0 + cc] = T[cc * 33 + rr];
        }
        return;
    }

    if (bid < 1056) {
        // -------- w1 [128][256] -> W1t [256][128]
        const int tile = bid - 1024;              // 0..31: 8 e-tiles x 4 j-tiles
        const int e0 = (tile >> 2) * 32, j0 = (tile & 3) * 32;
        __shared__ float T[32 * 33];
        const int cc = t & 31, r8 = t >> 5;
#pragma unroll
        for (int p = 0; p < 4; ++p) {
            int jj = r8 + 8 * p;
            T[jj * 33 + cc] = w1[(size_t)(j0 + jj) * 256 + e0 + cc];
        }
        __syncthreads();
#pragma unroll
        for (int p = 0; p < 4; ++p) {
            int ee = r8 + 8 * p;
            W1t[(size_t)(e0 + ee) * 128 + j0 + cc] = T[cc * 33 + ee];
        }
        return;
    }

    // -------- vector blocks
    const int vb = bid - 1120;
    if (vb < 4) { // c_l[d] = ub_l[d] - sum_k U_l[d][k]*(pb_l[k] + 0.5*pb_{l+1}[k])
        const int l = vb;
        __shared__ float v[256];
        v[t] = (l < 3) ? pred_b[l * 256 + t] + 0.5f * pred_b[(l + 1) * 256 + t]
                       : pred_b[3 * 256 + t];
        __syncthreads();
        const float* U = upd_w + (size_t)l * DD + (size_t)t * 256;
        float acc = 0.f;
#pragma unroll 8
        for (int k = 0; k < 256; k += 4) {
            float4 u = *(const float4*)&U[k];
            acc += u.x * v[k] + u.y * v[k + 1] + u.z * v[k + 2] + u.w * v[k + 3];
        }
        cvec[l * 256 + t] = upd_b[l * 256 + t] - acc;
        return;
    }
    { // vb==4: vsk/ksb/skb from sw/sb; vb==5: vse/keb/ekb from ew/eb
        const float* W = (vb == 4) ? sw : ew;
        const float* bb = (vb == 4) ? sb : eb;
        float* vout = (vb == 4) ? vsk : vse;
        float* bout = (vb == 4) ? ksb : keb;
        __shared__ float kbv[256], bbv[256], red[256];
        kbv[t] = kb[t]; bbv[t] = bb[t];
        __syncthreads();
        float a1 = 0.f, a2 = 0.f;
#pragma unroll 4
        for (int k = 0; k < 256; ++k) {
            a1 += W[(size_t)k * 256 + t] * kbv[k];
            a2 += kw[(size_t)k * 256 + t] * bbv[k];
        }
        vout[t] = a1; bout[t] = a2;
        red[t] = kbv[t] * bbv[t];
        __syncthreads();
        for (int s = 128; s > 0; s >>= 1) {
            if (t < s) red[t] += red[t + s];
            __syncthreads();
        }
        if (t == 0) scal[vb - 4] = red[0];
        return;
    }
}

// ---------------------------------------------------------------------------
// k_init: per-row init chain using transposed init weights (coalesced).
// Writes all 4 initial reps into rA[row][l*256+d] and ff.
// ---------------------------------------------------------------------------
__global__ __launch_bounds__(256) void k_init(const float* __restrict__ partial,
                                              const float* __restrict__ CMI,
                                              const float* __restrict__ init_b,
                                              float* __restrict__ rA,
                                              float* __restrict__ ff)
{
    const int row = blockIdx.x, t = threadIdx.x;
    __shared__ float xs[256];
    {
        const float* p = partial + (size_t)row * 4 * 256 + t;
        xs[t] = (p[0] + p[256] + p[512] + p[768]) * (1.f / 512.f);
    }
    float* rrow = rA + (size_t)row * 1024;
    for (int il = 0; il < 4; ++il) {
        __syncthreads();
        const float* M = CMI + (size_t)il * DD + t;
        float a0 = 0.f, a1 = 0.f, a2 = 0.f, a3 = 0.f;
#pragma unroll 8
        for (int k = 0; k < 256; k += 4) {
            float4 xv = *(const float4*)&xs[k];
            a0 += M[(size_t)(k + 0) * 256] * xv.x;
            a1 += M[(size_t)(k + 1) * 256] * xv.y;
            a2 += M[(size_t)(k + 2) * 256] * xv.z;
            a3 += M[(size_t)(k + 3) * 256] * xv.w;
        }
        float vx = tanhf(a0 + a1 + a2 + a3 + init_b[il * 256 + t]);
        __syncthreads();
        xs[t] = vx;
        rrow[il * 256 + t] = vx;
        if (il == 3) ff[(size_t)row * 256 + t] = vx;
    }
}

// ---------------------------------------------------------------------------
// k_stage: one refinement iteration.
//  z_l = sum_j CM[l*3+j] (transposed-apply) . r_{slo+j} + cvec_l (+rc0 for l=0)
//  r_new = r + 0.1*tanh(z)
// grid 512 = 16 rowtiles x (4 layers x 8 coltiles); block 256 = 16 rows x 16 dpairs
// ---------------------------------------------------------------------------
__global__ __launch_bounds__(256) void k_stage(const float* __restrict__ rcur,
                                               const float* __restrict__ CM,
                                               const float* __restrict__ cvec,
                                               const float* __restrict__ rc0,
                                               float* __restrict__ rnxt)
{
    __shared__ float As[16 * LDA];
    const int bid = blockIdx.x;
    const int t = threadIdx.x;
    const int rowtile = bid >> 5, ct = bid & 31;
    const int l = ct >> 3, d0 = (ct & 7) * 32;
    const int slo = (l == 0) ? 0 : (l - 1);
    const int shi = (l == 3) ? 3 : (l + 1);
    const int nj = shi - slo + 1;
    const int ks4 = (nj * 256) >> 2;
    const int r0 = rowtile * 16;
    const int row = t >> 4, dp = t & 15;
    {
        const float* src = rcur + (size_t)(r0 + row) * 1024 + slo * 256;
        float* dst = As + row * LDA;
        for (int c = dp; c < ks4; c += 16)
            *(float4*)&dst[4 * c] = *(const float4*)&src[4 * c];
    }
    __syncthreads();
    const float* Arow = As + row * LDA;
    float4 acc0 = {0.f, 0.f, 0.f, 0.f}, acc1 = {0.f, 0.f, 0.f, 0.f};
    for (int j = 0; j < nj; ++j) {
        const float* Mp = CM + (size_t)(l * 3 + j) * DD + d0 + 2 * dp;
        const float* Ax = Arow + j * 256;
#pragma unroll 8
        for (int k = 0; k < 256; k += 4) {
            float4 a = *(const float4*)&Ax[k];
            float2 m0 = *(const float2*)&Mp[(size_t)(k + 0) * 256];
            float2 m1 = *(const float2*)&Mp[(size_t)(k + 1) * 256];
            float2 m2 = *(const float2*)&Mp[(size_t)(k + 2) * 256];
            float2 m3 = *(const float2*)&Mp[(size_t)(k + 3) * 256];
            acc0.x += a.x * m0.x; acc0.y += a.y * m1.x;
            acc0.z += a.z * m2.x; acc0.w += a.w * m3.x;
            acc1.x += a.x * m0.y; acc1.y += a.y * m1.y;
            acc1.z += a.z * m2.y; acc1.w += a.w * m3.y;
        }
    }
    const int dcol = d0 + 2 * dp;
    float z0 = acc0.x + acc0.y + acc0.z + acc0.w + cvec[l * 256 + dcol];
    float z1 = acc1.x + acc1.y + acc1.z + acc1.w + cvec[l * 256 + dcol + 1];
    if (l == 0) {
        z0 += rc0[(size_t)(r0 + row) * 256 + dcol];
        z1 += rc0[(size_t)(r0 + row) * 256 + dcol + 1];
    }
    const int aself = (l - slo) * 256 + dcol;
    float ro0 = Arow[aself], ro1 = Arow[aself + 1];
    float2 outv = make_float2(ro0 + 0.1f * tanhf(z0), ro1 + 0.1f * tanhf(z1));
    *(float2*)&rnxt[(size_t)(r0 + row) * 1024 + l * 256 + dcol] = outv;
}

// ---------------------------------------------------------------------------
// k_heads: per-row head computations (refined, sqk/eqk/sqb/eqb, answerable).
// ---------------------------------------------------------------------------
__global__ __launch_bounds__(256) void k_heads(const float* __restrict__ rA,
    const float* __restrict__ ff,
    const float* __restrict__ KSt, const float* __restrict__ KEt,
    const float* __restrict__ ksb, const float* __restrict__ keb,
    const float* __restrict__ vsk, const float* __restrict__ vse,
    const float* __restrict__ scal,
    const float* __restrict__ W1t, const float* __restrict__ b1,
    const float* __restrict__ w2, const float* __restrict__ b2,
    float* __restrict__ sqk, float* __restrict__ eqk,
    float* __restrict__ sqb, float* __restrict__ eqb,
    float* __restrict__ out)
{
    const int row = blockIdx.x, t = threadIdx.x;
    __shared__ float xs[256];
    __shared__ float red[256];
    __shared__ float hp[256];
    __shared__ float hs[128];
    xs[t] = rA[(size_t)row * 1024 + 768 + t] + ff[(size_t)row * 256 + t];
    __syncthreads();
    {
        float a0 = 0.f, a1 = 0.f, a2 = 0.f, a3 = 0.f;
        float e0 = 0.f, e1 = 0.f, e2 = 0.f, e3 = 0.f;
        const float* KS = KSt + t;
        const float* KE = KEt + t;
#pragma unroll 4
        for (int f = 0; f < 256; f += 4) {
            float4 xv = *(const float4*)&xs[f];
            a0 += KS[(size_t)(f + 0) * 256] * xv.x; a1 += KS[(size_t)(f + 1) * 256] * xv.y;
            a2 += KS[(size_t)(f + 2) * 256] * xv.z; a3 += KS[(size_t)(f + 3) * 256] * xv.w;
            e0 += KE[(size_t)(f + 0) * 256] * xv.x; e1 += KE[(size_t)(f + 1) * 256] * xv.y;
            e2 += KE[(size_t)(f + 2) * 256] * xv.z; e3 += KE[(size_t)(f + 3) * 256] * xv.w;
        }
        sqk[(size_t)row * 256 + t] = a0 + a1 + a2 + a3 + ksb[t];
        eqk[(size_t)row * 256 + t] = e0 + e1 + e2 + e3 + keb[t];
    }
    red[t] = vsk[t] * xs[t];
    __syncthreads();
    for (int s = 128; s > 0; s >>= 1) { if (t < s) red[t] += red[t + s]; __syncthreads(); }
    if (t == 0) sqb[row] = red[0] + scal[0];
    __syncthreads();
    red[t] = vse[t] * xs[t];
    __syncthreads();
    for (int s = 128; s > 0; s >>= 1) { if (t < s) red[t] += red[t + s]; __syncthreads(); }
    if (t == 0) eqb[row] = red[0] + scal[1];
    __syncthreads();
    {
        const int j = t & 127, half = t >> 7;
        float a = 0.f;
        const float* W = W1t + (size_t)half * 128 * 128 + j;
        const float* xh = &xs[half * 128];
#pragma unroll 8
        for (int e = 0; e < 128; ++e) a += W[(size_t)e * 128] * xh[e];
        hp[half * 128 + j] = a;
    }
    __syncthreads();
    if (t < 128) {
        float x = hp[t] + hp[128 + t] + b1[t];
        hs[t] = 0.5f * x * (1.f + erff(x * 0.70710678118654752f));
    }
    __syncthreads();
    if (t < 128) { red[t] = hs[t] * w2[t]; red[128 + t] = hs[t] * w2[128 + t]; }
    __syncthreads();
    for (int s = 64; s > 0; s >>= 1) {
        if (t < s) red[t] += red[t + s];
        else if (t >= 128 && t < 128 + s) red[t] += red[t + s];
        __syncthreads();
    }
    if (t == 0)   out[2 * NB * NS + row * 2 + 0] = red[0] + b2[0];
    if (t == 128) out[2 * NB * NS + row * 2 + 1] = red[128] + b2[1];
}

// ---------------------------------------------------------------------------
// logits gather
// ---------------------------------------------------------------------------
__global__ __launch_bounds__(512) void k_logits(const int* __restrict__ ids,
                                                const float* __restrict__ emb,
                                                const float* __restrict__ pos,
                                                const float* __restrict__ sqk,
                                                const float* __restrict__ eqk,
                                                const float* __restrict__ sqb,
                                                const float* __restrict__ eqb,
                                                float* __restrict__ out) {
    const int bid = blockIdx.x;
    const int b = bid >> 2, q = bid & 3;
    const int t = threadIdx.x;
    __shared__ float sk[ND], ek[ND];
    __shared__ int sid[128];
    if (t < 256) sk[t] = sqk[b * ND + t];
    else ek[t - 256] = eqk[b * ND + t - 256];
    if (t < 128) sid[t] = ids[b * NS + q * 128 + t];
    __syncthreads();
    const int w = t >> 6, lane = t & 63;
    const float4 ks = *(const float4*)&sk[4 * lane];
    const float4 ke = *(const float4*)&ek[4 * lane];
    const float qbs = sqb[b], qbe = eqb[b];
    for (int si = w; si < 128; si += 8) {
        const int s = q * 128 + si;
        const int id = sid[si];
        const float4 e4 = *(const float4*)&emb[(size_t)id * ND + 4 * lane];
        const float4 p4 = *(const float4*)&pos[s * ND + 4 * lane];
        float vx = e4.x + p4.x, vy = e4.y + p4.y, vz = e4.z + p4.z, vw = e4.w + p4.w;
        float ds = vx * ks.x + vy * ks.y + vz * ks.z + vw * ks.w;
        float de = vx * ke.x + vy * ke.y + vz * ke.z + vw * ke.w;
#pragma unroll
        for (int off = 32; off >= 1; off >>= 1) {
            ds += __shfl_xor(ds, off);
            de += __shfl_xor(de, off);
        }
        if (lane == 0) {
            out[b * NS + s] = ds + qbs;
            out[NB * NS + b * NS + s] = de + qbe;
        }
    }
}

// ---------------------------------------------------------------------------
extern "C" void kernel_launch(void* const* d_in, const int* in_sizes, int n_in,
                              void* d_out, int out_size, void* d_ws, size_t ws_size,
                              hipStream_t stream) {
    const int*   ids    = (const int*)d_in[0];
    const float* emb    = (const float*)d_in[1];
    const float* pos    = (const float*)d_in[2];
    const float* init_w = (const float*)d_in[3];
    const float* init_b = (const float*)d_in[4];
    const float* pred_w = (const float*)d_in[5];
    const float* pred_b = (const float*)d_in[6];
    const float* upd_w  = (const float*)d_in[7];
    const float* upd_b  = (const float*)d_in[8];
    const float* sw     = (const float*)d_in[9];
    const float* sb     = (const float*)d_in[10];
    const float* ew     = (const float*)d_in[11];
    const float* eb     = (const float*)d_in[12];
    const float* kw     = (const float*)d_in[13];
    const float* kb     = (const float*)d_in[14];
    const float* w1     = (const float*)d_in[15];
    const float* b1     = (const float*)d_in[16];
    const float* w2     = (const float*)d_in[17];
    const float* b2     = (const float*)d_in[18];
    float* out = (float*)d_out;

    float* ws = (float*)d_ws;
    float* partial = ws;                 ws += 1024 * 256;
    float* rA      = ws;                 ws += 256 * 1024;
    float* rB      = ws;                 ws += 256 * 1024;
    float* ff      = ws;                 ws += 256 * 256;
    float* CM      = ws;                 ws += 12 * DD;
    float* CMI     = ws;                 ws += 4 * DD;
    float* KSt     = ws;                 ws += DD;
    float* KEt     = ws;                 ws += DD;
    float* W1t     = ws;                 ws += 256 * 128;
    float* cvec    = ws;                 ws += 4 * 256;
    float* rc0     = ws;                 ws += 256 * 256;
    float* vsk     = ws;                 ws += 256;
    float* vse     = ws;                 ws += 256;
    float* ksb     = ws;                 ws += 256;
    float* keb     = ws;                 ws += 256;
    float* scal    = ws;                 ws += 8;
    float* sqk     = ws;                 ws += 256 * 256;
    float* eqk     = ws;                 ws += 256 * 256;
    float* sqb     = ws;                 ws += 256;
    float* eqb     = ws;                 ws += 256;

    k_pool1<<<1024, 256, 0, stream>>>(ids, emb, pos, partial);

    k_prep<<<1126, 256, 0, stream>>>(pred_w, pred_b, upd_w, upd_b, init_w,
                                     sw, sb, ew, eb, kw, kb, w1, partial,
                                     CM, CMI, KSt, KEt, W1t,
                                     cvec, rc0, vsk, vse, ksb, keb, scal);

    k_init<<<256, 256, 0, stream>>>(partial, CMI, init_b, rA, ff);

    float* cur = rA;
    float* nxt = rB;
    for (int it = 0; it < NITERS; ++it) {
        k_stage<<<512, 256, 0, stream>>>(cur, CM, cvec, rc0, nxt);
        float* tmp = cur; cur = nxt; nxt = tmp;
    }
    // NITERS even -> final reps in rA

    k_heads<<<256, 256, 0, stream>>>(rA, ff, KSt, KEt, ksb, keb, vsk, vse, scal,
                                     W1t, b1, w2, b2, sqk, eqk, sqb, eqb, out);

    k_logits<<<1024, 512, 0, stream>>>(ids, emb, pos, sqk, eqk, sqb, eqb, out);
}